// Round 8
// baseline (150.216 us; speedup 1.0000x reference)
//
#include <hip/hip_runtime.h>
#include <hip/hip_fp16.h>

#define SS 2048
#define L2E 1.44269504088896340736f

typedef _Float16 f16x4 __attribute__((ext_vector_type(4)));
typedef _Float16 f16x8 __attribute__((ext_vector_type(8)));
typedef float f32x4 __attribute__((ext_vector_type(4)));

#define GLDS16(g, l) __builtin_amdgcn_global_load_lds(                          \
    (const __attribute__((address_space(1))) void*)(g),                         \
    (__attribute__((address_space(3))) void*)(l), 16, 0, 0)

// ---------------- Kernel A: QKV projection ----------------
// Fragment layouts:
//  qf/kf: [b][tile=s/16][ (feat/8)*16 + s%16 ][8 f16]; q pre-scaled by log2e;
//         feat group 3 (feats 24..31) ZERO (explicitly written below!).
//  vf (vd-blocks interleaved per lane so PV reads are one b128):
//     per 16k chunk: f16idx = (((k>>2)&3)*16 + (vd&15))*8 + (vd>>4)*4 + (k&3)
__global__ __launch_bounds__(256) void qkv_kernel(
    const float* __restrict__ x, const float* __restrict__ Wq,
    const float* __restrict__ Wk, const float* __restrict__ Wv,
    _Float16* __restrict__ qfp, _Float16* __restrict__ kfp,
    _Float16* __restrict__ vfp)
{
    __shared__ float xsT[64 * 64];     // [f][row], 16 KB
    __shared__ float wc[64 * 96];      // [f][c]: q24|k24|v32|pad16, 24 KB

    int t = threadIdx.x;
    // coalesced weight staging (b128 loads + b128 LDS writes)
    for (int i = t; i < 384; i += 256) {
        float4 v = ((const float4*)Wq)[i];
        int f = (i * 4) / 24, c = (i * 4) % 24;
        *(float4*)&wc[f * 96 + c] = v;
    }
    for (int i = t; i < 384; i += 256) {
        float4 v = ((const float4*)Wk)[i];
        int f = (i * 4) / 24, c = (i * 4) % 24;
        *(float4*)&wc[f * 96 + 24 + c] = v;
    }
    for (int i = t; i < 512; i += 256) {
        float4 v = ((const float4*)Wv)[i];
        int f = i >> 3, c = (i * 4) & 31;
        *(float4*)&wc[f * 96 + 48 + c] = v;
    }
    {   // zero pad cols 80..95
        int f = t >> 2, seg = t & 3;
        *(float4*)&wc[f * 96 + 80 + seg * 4] = (float4){0.f, 0.f, 0.f, 0.f};
    }
    // x tile staged transposed: xsT[f][row]
    long rowbase = (long)blockIdx.x * 64;
    const float4* xg = (const float4*)(x + rowbase * 64);
    for (int i = t; i < 1024; i += 256) {
        int r = i >> 4, c4 = i & 15;
        float4 v = xg[i];
        xsT[(c4 * 4 + 0) * 64 + r] = v.x;
        xsT[(c4 * 4 + 1) * 64 + r] = v.y;
        xsT[(c4 * 4 + 2) * 64 + r] = v.z;
        xsT[(c4 * 4 + 3) * 64 + r] = v.w;
    }
    __syncthreads();

    int rg = t >> 3;   // 32 row-groups of 2 rows
    int cg = t & 7;    // 8 col-groups of 12 cols
    float acc0[12], acc1[12];
    #pragma unroll
    for (int i = 0; i < 12; ++i) acc0[i] = acc1[i] = 0.f;

    #pragma unroll 4
    for (int f = 0; f < 64; ++f) {
        float2 xv = *(const float2*)&xsT[f * 64 + rg * 2];
        const float* wr = &wc[f * 96 + cg * 12];
        float4 wA = *(const float4*)(wr);
        float4 wB = *(const float4*)(wr + 4);
        float4 wC = *(const float4*)(wr + 8);
        float wv_[12] = {wA.x, wA.y, wA.z, wA.w, wB.x, wB.y, wB.z, wB.w,
                         wC.x, wC.y, wC.z, wC.w};
        #pragma unroll
        for (int i = 0; i < 12; ++i) {
            acc0[i] += xv.x * wv_[i];
            acc1[i] += xv.y * wv_[i];
        }
    }
    __syncthreads();                   // wc reads done; reuse as output staging
    _Float16* os = (_Float16*)wc;      // q[0..2047] | k[2048..4095] | v[4096..6143]

    // CRITICAL: zero feature-group 3 (feats 24..31) of q and k regions —
    // os aliases wc, so these slots otherwise hold stale weight bytes.
    if (t < 128) {
        int reg = t >> 6, rr = t & 63;
        *(f16x8*)&os[reg * 2048 + (rr >> 4) * 512 + (48 + (rr & 15)) * 8]
            = (f16x8){0, 0, 0, 0, 0, 0, 0, 0};
    }

    #pragma unroll
    for (int j = 0; j < 2; ++j) {
        int s = rg * 2 + j, st = s >> 4;
        const float* a = j ? acc1 : acc0;
        #pragma unroll
        for (int i = 0; i < 12; ++i) {
            int c = cg * 12 + i;
            if (c < 24) {
                os[st * 512 + ((c >> 3) * 16 + (s & 15)) * 8 + (c & 7)]
                    = (_Float16)(a[i] * L2E);
            } else if (c < 48) {
                int ck = c - 24;
                os[2048 + st * 512 + ((ck >> 3) * 16 + (s & 15)) * 8 + (ck & 7)]
                    = (_Float16)a[i];
            } else if (c < 80) {
                int vd = c - 48;
                os[4096 + st * 512 + (((s >> 2) & 3) * 16 + (vd & 15)) * 8
                   + (vd >> 4) * 4 + (s & 3)] = (_Float16)a[i];
            }
        }
    }
    __syncthreads();

    long blk = blockIdx.x;
    *(f16x8*)(qfp + blk * 2048 + t * 8) = *(const f16x8*)&os[t * 8];
    *(f16x8*)(kfp + blk * 2048 + t * 8) = *(const f16x8*)&os[2048 + t * 8];
    *(f16x8*)(vfp + blk * 2048 + t * 8) = *(const f16x8*)&os[4096 + t * 8];
}

// ---------------- Kernel B: partial column-softmax sums ----------------
// Wave owns 128 k (8 hoisted K-frags in regs); q-stream (16 x 1KB frags)
// staged through double-buffered LDS via global_load_lds (wave 0 stages).
__global__ __launch_bounds__(256) void stats_kernel(
    const _Float16* __restrict__ qf, const _Float16* __restrict__ kf,
    float* __restrict__ zpart)
{
    __shared__ __align__(16) _Float16 qbuf[2][1024];
    int w = blockIdx.x;
    int b = w >> 5, kb = (w >> 3) & 3, qs = w & 7;
    int t = threadIdx.x;
    int wv = t >> 6, l = t & 63, llo = l & 15, lhi = l >> 4;

    const _Float16* kfb = kf + ((long)b * 128 + kb * 32 + wv * 8) * 512 + l * 8;
    f16x8 af[8];
    #pragma unroll
    for (int j = 0; j < 8; ++j) af[j] = *(const f16x8*)(kfb + j * 512);

    const _Float16* qsrc = qf + ((long)b * 128 + qs * 16) * 512 + l * 8;
    f32x4 z[8];
    #pragma unroll
    for (int j = 0; j < 8; ++j) z[j] = (f32x4){0.f, 0.f, 0.f, 0.f};

    if (wv == 0) GLDS16(qsrc, &qbuf[0][0]);
    for (int it = 0; it < 16; ++it) {
        int cb = it & 1;
        __syncthreads();
        if (wv == 0 && it < 15) GLDS16(qsrc + (it + 1) * 512, &qbuf[cb ^ 1][0]);
        f16x8 q0 = *(const f16x8*)&qbuf[cb][l * 8];
        #pragma unroll
        for (int j = 0; j < 8; ++j) {
            f32x4 d = __builtin_amdgcn_mfma_f32_16x16x32_f16(af[j], q0,
                        (f32x4){0.f, 0.f, 0.f, 0.f}, 0, 0, 0);
            #pragma unroll
            for (int r = 0; r < 4; ++r) z[j][r] += __builtin_amdgcn_exp2f(d[r]);
        }
    }
    #pragma unroll
    for (int m = 1; m < 16; m <<= 1)
        #pragma unroll
        for (int j = 0; j < 8; ++j)
            #pragma unroll
            for (int r = 0; r < 4; ++r) z[j][r] += __shfl_xor(z[j][r], m, 64);
    if (llo == 0) {
        #pragma unroll
        for (int j = 0; j < 8; ++j)
            *(f32x4*)(zpart + ((long)qs * 32 + b) * SS + kb * 512 + wv * 128
                      + j * 16 + lhi * 4) = z[j];
    }
}

// ---------------- Kernel B2: finalize wneg = -log2(sum of partials) --------
__global__ __launch_bounds__(256) void finalize_kernel(
    const float* __restrict__ zpart, float* __restrict__ wneg)
{
    int i = blockIdx.x * 256 + threadIdx.x;
    float s = 0.f;
    #pragma unroll
    for (int qs = 0; qs < 8; ++qs) s += zpart[(long)qs * 32 * SS + i];
    wneg[i] = -__builtin_amdgcn_logf(s);
}

// ---------------- Kernel C: attention + output projection ----------------
// Block = 64 q-rows (4 q-frags in regs, shared by all waves); waves split k
// (512 each). K/V/w stream straight from L2 to registers (no LDS, no
// barriers in the main loop) -> pure TLP latency hiding at 16 waves/CU.
// Cross-wave h1 reduction via LDS, then MFMA output projection.
__global__ __launch_bounds__(256, 4) void attn_out_kernel(
    const _Float16* __restrict__ qf, const _Float16* __restrict__ kf,
    const _Float16* __restrict__ vf, const float* __restrict__ wneg,
    const float* __restrict__ Wh, float* __restrict__ out)
{
    __shared__ f32x4 red[4][8][64];    // 32 KB
    int w = blockIdx.x;
    int b = w >> 5, qblk = w & 31;
    int t = threadIdx.x;
    int wv = t >> 6, l = t & 63, llo = l & 15, lhi = l >> 4;

    const _Float16* qb = qf + ((long)b * 128 + qblk * 4) * 512 + l * 8;
    f16x8 qv[4];
    #pragma unroll
    for (int g = 0; g < 4; ++g) qv[g] = *(const f16x8*)(qb + g * 512);

    const _Float16* kg = kf + ((long)b * 128 + wv * 32) * 512 + l * 8;
    const _Float16* vg = vf + ((long)b * 128 + wv * 32) * 512 + l * 8;
    const float*    wg = wneg + (long)b * SS + wv * 512 + lhi * 4;

    f32x4 acc[4][2];
    #pragma unroll
    for (int g = 0; g < 4; ++g) {
        acc[g][0] = (f32x4){0.f, 0.f, 0.f, 0.f};
        acc[g][1] = (f32x4){0.f, 0.f, 0.f, 0.f};
    }

    #pragma unroll 2
    for (int i = 0; i < 32; ++i) {
        f16x8 kfr = *(const f16x8*)(kg + i * 512);
        float4 w4 = *(const float4*)(wg + i * 16);
        f16x8 v01 = *(const f16x8*)(vg + i * 512);
        f32x4 cw = {w4.x, w4.y, w4.z, w4.w};
        f16x4 v0 = {v01[0], v01[1], v01[2], v01[3]};
        f16x4 v1 = {v01[4], v01[5], v01[6], v01[7]};
        #pragma unroll
        for (int g = 0; g < 4; ++g) {
            f32x4 d = __builtin_amdgcn_mfma_f32_16x16x32_f16(kfr, qv[g], cw, 0, 0, 0);
            f16x4 pa;
            #pragma unroll
            for (int r = 0; r < 4; ++r) pa[r] = (_Float16)__builtin_amdgcn_exp2f(d[r]);
            acc[g][0] = __builtin_amdgcn_mfma_f32_16x16x16f16(v0, pa, acc[g][0], 0, 0, 0);
            acc[g][1] = __builtin_amdgcn_mfma_f32_16x16x16f16(v1, pa, acc[g][1], 0, 0, 0);
        }
    }

    // cross-wave reduction of partial h1^T
    #pragma unroll
    for (int g = 0; g < 4; ++g) {
        red[wv][g * 2][l]     = acc[g][0];
        red[wv][g * 2 + 1][l] = acc[g][1];
    }
    __syncthreads();

    // epilogue: wave wv produces output f-columns [wv*16, wv*16+16)
    f16x4 wlo, whi;
    #pragma unroll
    for (int j = 0; j < 4; ++j) {
        wlo[j] = (_Float16)Wh[(4 * lhi + j) * 64 + wv * 16 + llo];
        whi[j] = (_Float16)Wh[(16 + 4 * lhi + j) * 64 + wv * 16 + llo];
    }
    long q0 = (long)b * SS + qblk * 64;
    #pragma unroll
    for (int g = 0; g < 4; ++g) {
        f32x4 s0 = red[0][g * 2][l] + red[1][g * 2][l]
                 + red[2][g * 2][l] + red[3][g * 2][l];
        f32x4 s1 = red[0][g * 2 + 1][l] + red[1][g * 2 + 1][l]
                 + red[2][g * 2 + 1][l] + red[3][g * 2 + 1][l];
        f16x4 h0, h1;
        #pragma unroll
        for (int r = 0; r < 4; ++r) {
            h0[r] = (_Float16)s0[r];
            h1[r] = (_Float16)s1[r];
        }
        f32x4 o = __builtin_amdgcn_mfma_f32_16x16x16f16(wlo, h0,
                    (f32x4){0.f, 0.f, 0.f, 0.f}, 0, 0, 0);
        o = __builtin_amdgcn_mfma_f32_16x16x16f16(whi, h1, o, 0, 0, 0);
        *(f32x4*)(out + (q0 + g * 16 + llo) * 64 + wv * 16 + 4 * lhi) = o;
    }
}

extern "C" void kernel_launch(void* const* d_in, const int* in_sizes, int n_in,
                              void* d_out, int out_size, void* d_ws, size_t ws_size,
                              hipStream_t stream) {
    const float* x  = (const float*)d_in[0];
    const float* Wq = (const float*)d_in[1];
    const float* Wk = (const float*)d_in[2];
    const float* Wv = (const float*)d_in[3];
    const float* Wh = (const float*)d_in[4];
    float* out = (float*)d_out;

    char* ws = (char*)d_ws;
    _Float16* qf  = (_Float16*)(ws);                           // 4 MB
    _Float16* kf  = (_Float16*)(ws + (4l << 20));              // 4 MB
    _Float16* vf  = (_Float16*)(ws + (8l << 20));              // 4 MB
    float* wneg   = (float*)(ws + (12l << 20));                // 256 KB
    float* zpart  = (float*)(ws + (12l << 20) + (256l << 10)); // 2 MB

    qkv_kernel<<<1024, 256, 0, stream>>>(x, Wq, Wk, Wv, qf, kf, vf);
    stats_kernel<<<1024, 256, 0, stream>>>(qf, kf, zpart);
    finalize_kernel<<<256, 256, 0, stream>>>(zpart, wneg);
    attn_out_kernel<<<1024, 256, 0, stream>>>(qf, kf, vf, wneg, Wh, out);
}

// Round 9
// 81.372 us; speedup vs baseline: 1.8460x; 1.8460x over previous
//
#include <hip/hip_runtime.h>
#include <hip/hip_fp16.h>

#define SS 2048
#define L2E 1.44269504088896340736f

typedef _Float16 f16x4 __attribute__((ext_vector_type(4)));
typedef _Float16 f16x8 __attribute__((ext_vector_type(8)));
typedef float f32x4 __attribute__((ext_vector_type(4)));

// ---------------- Kernel A: QKV projection ----------------
// Fragment layouts:
//  qf/kf: [b][tile=s/16][ (feat/8)*16 + s%16 ][8 f16]; q pre-scaled by log2e;
//         feat group 3 (feats 24..31) ZERO.
//  vf (vd-blocks interleaved per lane so PV reads are one b128):
//     per 16k chunk: f16idx = (((k>>2)&3)*16 + (vd&15))*8 + (vd>>4)*4 + (k&3)
__global__ __launch_bounds__(256) void qkv_kernel(
    const float* __restrict__ x, const float* __restrict__ Wq,
    const float* __restrict__ Wk, const float* __restrict__ Wv,
    _Float16* __restrict__ qfp, _Float16* __restrict__ kfp,
    _Float16* __restrict__ vfp)
{
    __shared__ float xsT[64 * 64];     // [f][row], 16 KB
    __shared__ float wc[64 * 96];      // [f][c]: q24|k24|v32|pad16, 24 KB

    int t = threadIdx.x;
    for (int i = t; i < 384; i += 256) {
        float4 v = ((const float4*)Wq)[i];
        int f = (i * 4) / 24, c = (i * 4) % 24;
        *(float4*)&wc[f * 96 + c] = v;
    }
    for (int i = t; i < 384; i += 256) {
        float4 v = ((const float4*)Wk)[i];
        int f = (i * 4) / 24, c = (i * 4) % 24;
        *(float4*)&wc[f * 96 + 24 + c] = v;
    }
    for (int i = t; i < 512; i += 256) {
        float4 v = ((const float4*)Wv)[i];
        int f = i >> 3, c = (i * 4) & 31;
        *(float4*)&wc[f * 96 + 48 + c] = v;
    }
    {
        int f = t >> 2, seg = t & 3;
        *(float4*)&wc[f * 96 + 80 + seg * 4] = (float4){0.f, 0.f, 0.f, 0.f};
    }
    long rowbase = (long)blockIdx.x * 64;
    const float4* xg = (const float4*)(x + rowbase * 64);
    for (int i = t; i < 1024; i += 256) {
        int r = i >> 4, c4 = i & 15;
        float4 v = xg[i];
        xsT[(c4 * 4 + 0) * 64 + r] = v.x;
        xsT[(c4 * 4 + 1) * 64 + r] = v.y;
        xsT[(c4 * 4 + 2) * 64 + r] = v.z;
        xsT[(c4 * 4 + 3) * 64 + r] = v.w;
    }
    __syncthreads();

    int rg = t >> 3;   // 32 row-groups of 2 rows
    int cg = t & 7;    // 8 col-groups of 12 cols
    float acc0[12], acc1[12];
    #pragma unroll
    for (int i = 0; i < 12; ++i) acc0[i] = acc1[i] = 0.f;

    #pragma unroll 4
    for (int f = 0; f < 64; ++f) {
        float2 xv = *(const float2*)&xsT[f * 64 + rg * 2];
        const float* wr = &wc[f * 96 + cg * 12];
        float4 wA = *(const float4*)(wr);
        float4 wB = *(const float4*)(wr + 4);
        float4 wC = *(const float4*)(wr + 8);
        float wv_[12] = {wA.x, wA.y, wA.z, wA.w, wB.x, wB.y, wB.z, wB.w,
                         wC.x, wC.y, wC.z, wC.w};
        #pragma unroll
        for (int i = 0; i < 12; ++i) {
            acc0[i] += xv.x * wv_[i];
            acc1[i] += xv.y * wv_[i];
        }
    }
    __syncthreads();                   // wc reads done; reuse as output staging
    _Float16* os = (_Float16*)wc;      // q | k | v fragment regions

    // zero feature-group 3 (feats 24..31) of q and k regions (os aliases wc)
    if (t < 128) {
        int reg = t >> 6, rr = t & 63;
        *(f16x8*)&os[reg * 2048 + (rr >> 4) * 512 + (48 + (rr & 15)) * 8]
            = (f16x8){0, 0, 0, 0, 0, 0, 0, 0};
    }

    #pragma unroll
    for (int j = 0; j < 2; ++j) {
        int s = rg * 2 + j, st = s >> 4;
        const float* a = j ? acc1 : acc0;
        #pragma unroll
        for (int i = 0; i < 12; ++i) {
            int c = cg * 12 + i;
            if (c < 24) {
                os[st * 512 + ((c >> 3) * 16 + (s & 15)) * 8 + (c & 7)]
                    = (_Float16)(a[i] * L2E);
            } else if (c < 48) {
                int ck = c - 24;
                os[2048 + st * 512 + ((ck >> 3) * 16 + (s & 15)) * 8 + (ck & 7)]
                    = (_Float16)a[i];
            } else if (c < 80) {
                int vd = c - 48;
                os[4096 + st * 512 + (((s >> 2) & 3) * 16 + (vd & 15)) * 8
                   + (vd >> 4) * 4 + (s & 3)] = (_Float16)a[i];
            }
        }
    }
    __syncthreads();

    long blk = blockIdx.x;
    *(f16x8*)(qfp + blk * 2048 + t * 8) = *(const f16x8*)&os[t * 8];
    *(f16x8*)(kfp + blk * 2048 + t * 8) = *(const f16x8*)&os[2048 + t * 8];
    *(f16x8*)(vfp + blk * 2048 + t * 8) = *(const f16x8*)&os[4096 + t * 8];
}

// ---------------- Kernel B: partial column-softmax sums ----------------
// ROUND-6-PROVEN structure: wave owns 64 k (4 hoisted K-frags, 16 VGPR),
// streams 256 q as 16 direct global b128 loads. No LDS, no barriers.
__global__ __launch_bounds__(256) void stats_kernel(
    const _Float16* __restrict__ qf, const _Float16* __restrict__ kf,
    float* __restrict__ zpart)
{
    int w = blockIdx.x;
    int b = w & 31, kb = (w >> 5) & 7, qs = w >> 8;
    int t = threadIdx.x;
    int wv = t >> 6, l = t & 63, llo = l & 15, lhi = l >> 4;

    const _Float16* kfb = kf + ((long)b * 128 + kb * 16 + wv * 4) * 512 + l * 8;
    f16x8 af[4];
    #pragma unroll
    for (int kt = 0; kt < 4; ++kt) af[kt] = *(const f16x8*)(kfb + kt * 512);

    const _Float16* qb = qf + ((long)b * 128 + qs * 16) * 512 + l * 8;
    f32x4 z[4] = {{0,0,0,0},{0,0,0,0},{0,0,0,0},{0,0,0,0}};

    #pragma unroll 4
    for (int qi = 0; qi < 16; ++qi) {
        f16x8 q0 = *(const f16x8*)(qb + qi * 512);
        #pragma unroll
        for (int kt = 0; kt < 4; ++kt) {
            f32x4 d = __builtin_amdgcn_mfma_f32_16x16x32_f16(af[kt], q0,
                        (f32x4){0.f, 0.f, 0.f, 0.f}, 0, 0, 0);
            #pragma unroll
            for (int r = 0; r < 4; ++r) z[kt][r] += __builtin_amdgcn_exp2f(d[r]);
        }
    }
    #pragma unroll
    for (int m = 1; m < 16; m <<= 1)
        #pragma unroll
        for (int kt = 0; kt < 4; ++kt)
            #pragma unroll
            for (int r = 0; r < 4; ++r) z[kt][r] += __shfl_xor(z[kt][r], m, 64);
    if (llo == 0) {
        #pragma unroll
        for (int kt = 0; kt < 4; ++kt)
            *(f32x4*)(zpart + ((long)qs * 32 + b) * SS + kb * 256 + wv * 64
                      + kt * 16 + lhi * 4) = z[kt];
    }
}

// ---------------- Kernel B2: finalize wneg = -log2(sum of partials) --------
__global__ __launch_bounds__(256) void finalize_kernel(
    const float* __restrict__ zpart, float* __restrict__ wneg)
{
    int i = blockIdx.x * 256 + threadIdx.x;
    float s = 0.f;
    #pragma unroll
    for (int qs = 0; qs < 8; ++qs) s += zpart[(long)qs * 32 * SS + i];
    wneg[i] = -__builtin_amdgcn_logf(s);
}

// ---------------- Kernel C: attention + output projection ----------------
// Block = 64 q-rows (4 q-frags in regs, shared); waves split k (512 each).
// K/V/w stream straight from L2 to registers; no main-loop barriers.
__global__ __launch_bounds__(256, 4) void attn_out_kernel(
    const _Float16* __restrict__ qf, const _Float16* __restrict__ kf,
    const _Float16* __restrict__ vf, const float* __restrict__ wneg,
    const float* __restrict__ Wh, float* __restrict__ out)
{
    __shared__ f32x4 red[4][8][64];    // 32 KB
    int w = blockIdx.x;
    int b = w >> 5, qblk = w & 31;
    int t = threadIdx.x;
    int wv = t >> 6, l = t & 63, llo = l & 15, lhi = l >> 4;

    const _Float16* qb = qf + ((long)b * 128 + qblk * 4) * 512 + l * 8;
    f16x8 qv[4];
    #pragma unroll
    for (int g = 0; g < 4; ++g) qv[g] = *(const f16x8*)(qb + g * 512);

    const _Float16* kg = kf + ((long)b * 128 + wv * 32) * 512 + l * 8;
    const _Float16* vg = vf + ((long)b * 128 + wv * 32) * 512 + l * 8;
    const float*    wg = wneg + (long)b * SS + wv * 512 + lhi * 4;

    f32x4 acc[4][2];
    #pragma unroll
    for (int g = 0; g < 4; ++g) {
        acc[g][0] = (f32x4){0.f, 0.f, 0.f, 0.f};
        acc[g][1] = (f32x4){0.f, 0.f, 0.f, 0.f};
    }

    #pragma unroll 2
    for (int i = 0; i < 32; ++i) {
        f16x8 kfr = *(const f16x8*)(kg + i * 512);
        float4 w4 = *(const float4*)(wg + i * 16);
        f16x8 v01 = *(const f16x8*)(vg + i * 512);
        f32x4 cw = {w4.x, w4.y, w4.z, w4.w};
        f16x4 v0 = {v01[0], v01[1], v01[2], v01[3]};
        f16x4 v1 = {v01[4], v01[5], v01[6], v01[7]};
        #pragma unroll
        for (int g = 0; g < 4; ++g) {
            f32x4 d = __builtin_amdgcn_mfma_f32_16x16x32_f16(kfr, qv[g], cw, 0, 0, 0);
            f16x4 pa;
            #pragma unroll
            for (int r = 0; r < 4; ++r) pa[r] = (_Float16)__builtin_amdgcn_exp2f(d[r]);
            acc[g][0] = __builtin_amdgcn_mfma_f32_16x16x16f16(v0, pa, acc[g][0], 0, 0, 0);
            acc[g][1] = __builtin_amdgcn_mfma_f32_16x16x16f16(v1, pa, acc[g][1], 0, 0, 0);
        }
    }

    #pragma unroll
    for (int g = 0; g < 4; ++g) {
        red[wv][g * 2][l]     = acc[g][0];
        red[wv][g * 2 + 1][l] = acc[g][1];
    }
    __syncthreads();

    f16x4 wlo, whi;
    #pragma unroll
    for (int j = 0; j < 4; ++j) {
        wlo[j] = (_Float16)Wh[(4 * lhi + j) * 64 + wv * 16 + llo];
        whi[j] = (_Float16)Wh[(16 + 4 * lhi + j) * 64 + wv * 16 + llo];
    }
    long q0 = (long)b * SS + qblk * 64;
    #pragma unroll
    for (int g = 0; g < 4; ++g) {
        f32x4 s0 = red[0][g * 2][l] + red[1][g * 2][l]
                 + red[2][g * 2][l] + red[3][g * 2][l];
        f32x4 s1 = red[0][g * 2 + 1][l] + red[1][g * 2 + 1][l]
                 + red[2][g * 2 + 1][l] + red[3][g * 2 + 1][l];
        f16x4 h0, h1;
        #pragma unroll
        for (int r = 0; r < 4; ++r) {
            h0[r] = (_Float16)s0[r];
            h1[r] = (_Float16)s1[r];
        }
        f32x4 o = __builtin_amdgcn_mfma_f32_16x16x16f16(wlo, h0,
                    (f32x4){0.f, 0.f, 0.f, 0.f}, 0, 0, 0);
        o = __builtin_amdgcn_mfma_f32_16x16x16f16(whi, h1, o, 0, 0, 0);
        *(f32x4*)(out + (q0 + g * 16 + llo) * 64 + wv * 16 + 4 * lhi) = o;
    }
}

extern "C" void kernel_launch(void* const* d_in, const int* in_sizes, int n_in,
                              void* d_out, int out_size, void* d_ws, size_t ws_size,
                              hipStream_t stream) {
    const float* x  = (const float*)d_in[0];
    const float* Wq = (const float*)d_in[1];
    const float* Wk = (const float*)d_in[2];
    const float* Wv = (const float*)d_in[3];
    const float* Wh = (const float*)d_in[4];
    float* out = (float*)d_out;

    char* ws = (char*)d_ws;
    _Float16* qf  = (_Float16*)(ws);                           // 4 MB
    _Float16* kf  = (_Float16*)(ws + (4l << 20));              // 4 MB
    _Float16* vf  = (_Float16*)(ws + (8l << 20));              // 4 MB
    float* wneg   = (float*)(ws + (12l << 20));                // 256 KB
    float* zpart  = (float*)(ws + (12l << 20) + (256l << 10)); // 2 MB

    qkv_kernel<<<1024, 256, 0, stream>>>(x, Wq, Wk, Wv, qf, kf, vf);
    stats_kernel<<<2048, 256, 0, stream>>>(qf, kf, zpart);
    finalize_kernel<<<256, 256, 0, stream>>>(zpart, wneg);
    attn_out_kernel<<<1024, 256, 0, stream>>>(qf, kf, vf, wneg, Wh, out);
}